// Round 6
// baseline (74.036 us; speedup 1.0000x reference)
//
#include <hip/hip_runtime.h>

// YOLOv3 layer = per-batch 255x2704 transpose + per-channel elementwise map.
//   out[b][hw][c] = f_c(in[b][c][hw]),  c = a*85 + d
//   d==0: (sig(x)+w)/52   d==1: (sig(x)+h)/52
//   d==2: (aw[a]/416)*exp(x)   d==3: (ah[a]/416)*exp(x)   d>=4: sig(x)
// plus trailing scalar out[64*689520] = -1.0f
//
// R5 lesson: 208B read runs helped (-6us). Occupancy fell to 52% (2 blocks/CU
// effective) -> load/store phases don't overlap across blocks. This round:
// 640 threads (10 waves) x 3 LDS-resident blocks = 30/32 waves, plus chunked
// XCD swizzle (3328 = 8*416) so same-b blocks share an XCD's L2/DRAM pages.

#define CH     255
#define HWTOT  2704
#define NB     64
#define BOX    85
#define PER_B  (CH * HWTOT)        // 689520
#define HWROWS 52
#define HWBLKS (HWTOT / HWROWS)    // 52  (hwblk IS h)
#define SLOTS  (CH * (HWROWS/4))   // 3315 float4 slots per tile
#define THREADS 640
#define NSLOT   6                  // ceil(3315/640)
#define NWG     (HWBLKS * NB)      // 3328 = 8 * 416
#define CPX     (NWG / 8)          // 416 blocks per XCD chunk

typedef float vfloat4 __attribute__((ext_vector_type(4)));

__global__ __launch_bounds__(THREADS) void yolo_kernel(const float* __restrict__ in,
                                                       float* __restrict__ out) {
    __shared__ float tile[HWROWS * CH];   // [w][c], 53040 B

    const int t    = threadIdx.x;
    const int bid0 = blockIdx.x;
    // chunked XCD swizzle: XCD k gets bids [k*416, (k+1)*416) -> same-b locality
    const int bid  = (bid0 % 8) * CPX + bid0 / 8;
    const int hwblk = bid % HWBLKS;       // == h (0..51), block-uniform
    const int b     = bid / HWBLKS;
    const int hw0   = hwblk * HWROWS;

    const float* inb  = in + (size_t)b * PER_B + hw0;
    const float hnorm = (float)hwblk * (1.0f / 52.0f);   // h/52

    // ---- load: 6 batched float4 loads; 208B-contiguous run per c-row ----
    vfloat4 v[NSLOT];
    int cs[NSLOT], gs[NSLOT];
    #pragma unroll
    for (int k = 0; k < NSLOT; ++k) {
        const int s   = t + THREADS * k;
        const int scl = (s < SLOTS) ? s : (SLOTS - 1);         // clamp tail
        const int c   = (int)(((unsigned)scl * 20165u) >> 18); // scl/13 (magic)
        const int g   = scl - c * 13;                          // float4 group in row
        cs[k] = c; gs[k] = g;
        v[k] = *reinterpret_cast<const vfloat4*>(inb + (size_t)c * HWTOT + g * 4);
    }

    // ---- branchless transform + LDS scatter ----
    #pragma unroll
    for (int k = 0; k < NSLOT; ++k) {
        const int s = t + THREADS * k;
        const int c = cs[k], g = gs[k];
        const int a = (c >= 2*BOX) ? 2 : (c >= BOX) ? 1 : 0;
        const int d = c - a * BOX;
        const float sw = (a==0) ? (10.0f/416.0f) : (a==1) ? (16.0f/416.0f) : (33.0f/416.0f);
        const float sh = (a==0) ? (13.0f/416.0f) : (a==1) ? (30.0f/416.0f) : (23.0f/416.0f);
        const float sc = (d == 2) ? sw : sh;
        const bool is_xy = (d < 2);
        const bool is_wh = (d == 2) | (d == 3);
        if (s < SLOTS) {
            #pragma unroll
            for (int j = 0; j < 4; ++j) {
                const float x  = v[k][j];
                const float e  = __expf(x);                           // serves both paths
                const float sg = e * __builtin_amdgcn_rcpf(1.0f + e); // sigmoid = e/(1+e)
                const float wn = (float)(g*4 + j) * (1.0f / 52.0f);   // w/52
                const float axy = (d == 0) ? wn : hnorm;
                float o = is_xy ? (sg * (1.0f/52.0f) + axy) : sg;
                o = is_wh ? (sc * e) : o;
                tile[(g*4 + j) * CH + c] = o;
            }
        }
    }

    __syncthreads();

    // ---- store: linear float4 copy of 53KB contiguous out span ----
    const vfloat4* t4 = reinterpret_cast<const vfloat4*>(tile);
    vfloat4* o4 = reinterpret_cast<vfloat4*>(out + (size_t)b * PER_B + (size_t)hw0 * CH);
    #pragma unroll
    for (int k = 0; k < NSLOT; ++k) {
        const int idx = t + THREADS * k;
        if (idx < SLOTS)
            o4[idx] = t4[idx];
    }

    if (t == 0 && bid0 == 0)
        out[(size_t)NB * PER_B] = -1.0f;   // trailing scalar output
}

extern "C" void kernel_launch(void* const* d_in, const int* in_sizes, int n_in,
                              void* d_out, int out_size, void* d_ws, size_t ws_size,
                              hipStream_t stream) {
    const float* x = (const float*)d_in[0];
    float* out = (float*)d_out;
    yolo_kernel<<<dim3(NWG), dim3(THREADS), 0, stream>>>(x, out);
}

// Round 7
// 71.182 us; speedup vs baseline: 1.0401x; 1.0401x over previous
//
#include <hip/hip_runtime.h>

// YOLOv3 layer = per-batch 255x2704 transpose + per-channel elementwise map.
//   out[b][hw][c] = f_c(in[b][c][hw]),  c = a*85 + d
//   d==0: (sig(x)+w)/52   d==1: (sig(x)+h)/52
//   d==2: (aw[a]/416)*exp(x)   d==3: (ah[a]/416)*exp(x)   d>=4: sig(x)
// plus trailing scalar out[64*689520] = -1.0f
//
// R6 lesson: time flat while HBM traffic dropped => not HBM-bound; occupancy
// pinned at ~2 blocks/CU (evidence: ~128KB effective LDS residency cap).
// This round: all 7 loads+transforms in registers up front (keeps 208B read
// runs), drain via HALF-size LDS (28.6KB) in two phases (rows 0-27 / 28-51)
// => 4 blocks x 8 waves = 32 waves/CU. Store spans stay linear float4.

#define CH     255
#define HWTOT  2704
#define NB     64
#define BOX    85
#define PER_B  (CH * HWTOT)        // 689520
#define HWROWS 52
#define HWBLKS (HWTOT / HWROWS)    // 52 (hwblk IS h)
#define SLOTS  (CH * (HWROWS/4))   // 3315 float4 slots per full tile
#define THREADS 512
#define NSLOT   7                  // ceil(3315/512)
#define GSPLIT  7                  // g<7 -> phase A (28 rows), else B (24 rows)
#define ROWS_A  28
#define F4_A    (ROWS_A * CH / 4)  // 1785 float4 in span A
#define F4_B    (SLOTS - F4_A)     // 1530 float4 in span B
#define LDSF    (ROWS_A * CH)      // 7140 floats = 28560 B
#define NWG     (HWBLKS * NB)      // 3328 = 8 * 416
#define CPX     (NWG / 8)

typedef float vfloat4 __attribute__((ext_vector_type(4)));

__global__ __launch_bounds__(THREADS, 8) void yolo_kernel(const float* __restrict__ in,
                                                          float* __restrict__ out) {
    __shared__ float tile[LDSF];   // 28560 B — half-tile staging buffer

    const int t    = threadIdx.x;
    const int bid0 = blockIdx.x;
    const int bid  = (bid0 % 8) * CPX + bid0 / 8;   // chunked XCD swizzle
    const int hwblk = bid % HWBLKS;                 // == h, block-uniform
    const int b     = bid / HWBLKS;
    const int hw0   = hwblk * HWROWS;

    const float* inb  = in + (size_t)b * PER_B + hw0;
    const float hnorm = (float)hwblk * (1.0f / 52.0f);

    // ---- all loads up front: 208B-contiguous run per c-row ----
    vfloat4 v[NSLOT];
    int cs[NSLOT], gs[NSLOT];
    #pragma unroll
    for (int k = 0; k < NSLOT; ++k) {
        const int s   = t + THREADS * k;
        const int scl = (s < SLOTS) ? s : (SLOTS - 1);
        const int c   = (int)(((unsigned)scl * 20165u) >> 18); // scl/13 (magic)
        const int g   = scl - c * 13;
        cs[k] = c; gs[k] = g;
        v[k] = *reinterpret_cast<const vfloat4*>(inb + (size_t)c * HWTOT + g * 4);
    }

    // ---- transform in registers (branchless; one exp serves both paths) ----
    #pragma unroll
    for (int k = 0; k < NSLOT; ++k) {
        const int c = cs[k], g = gs[k];
        const int a = (c >= 2*BOX) ? 2 : (c >= BOX) ? 1 : 0;
        const int d = c - a * BOX;
        const float sw = (a==0) ? (10.0f/416.0f) : (a==1) ? (16.0f/416.0f) : (33.0f/416.0f);
        const float sh = (a==0) ? (13.0f/416.0f) : (a==1) ? (30.0f/416.0f) : (23.0f/416.0f);
        const float sc = (d == 2) ? sw : sh;
        const bool is_xy = (d < 2);
        const bool is_wh = (d == 2) | (d == 3);
        #pragma unroll
        for (int j = 0; j < 4; ++j) {
            const float x  = v[k][j];
            const float e  = __expf(x);
            const float sg = e * __builtin_amdgcn_rcpf(1.0f + e);
            const float wn = (float)(g*4 + j) * (1.0f / 52.0f);
            const float axy = (d == 0) ? wn : hnorm;
            float o = is_xy ? (sg * (1.0f/52.0f) + axy) : sg;
            o = is_wh ? (sc * e) : o;
            v[k][j] = o;
        }
    }

    float* outb = out + (size_t)b * PER_B + (size_t)hw0 * CH;

    // ---- phase A: rows 0..27 (g<7) through LDS, linear f4 store ----
    #pragma unroll
    for (int k = 0; k < NSLOT; ++k) {
        const int s = t + THREADS * k;
        if (s < SLOTS && gs[k] < GSPLIT) {
            #pragma unroll
            for (int j = 0; j < 4; ++j)
                tile[(gs[k]*4 + j) * CH + cs[k]] = v[k][j];
        }
    }
    __syncthreads();
    {
        const vfloat4* t4 = reinterpret_cast<const vfloat4*>(tile);
        vfloat4* o4 = reinterpret_cast<vfloat4*>(outb);
        #pragma unroll
        for (int i = 0; i < 4; ++i) {
            const int idx = t + THREADS * i;
            if (idx < F4_A) o4[idx] = t4[idx];
        }
    }
    __syncthreads();

    // ---- phase B: rows 28..51 (g>=7), reuse same LDS buffer ----
    #pragma unroll
    for (int k = 0; k < NSLOT; ++k) {
        const int s = t + THREADS * k;
        if (s < SLOTS && gs[k] >= GSPLIT) {
            #pragma unroll
            for (int j = 0; j < 4; ++j)
                tile[((gs[k]-GSPLIT)*4 + j) * CH + cs[k]] = v[k][j];
        }
    }
    __syncthreads();
    {
        const vfloat4* t4 = reinterpret_cast<const vfloat4*>(tile);
        vfloat4* o4 = reinterpret_cast<vfloat4*>(outb + ROWS_A * CH);
        #pragma unroll
        for (int i = 0; i < 3; ++i) {
            const int idx = t + THREADS * i;
            if (idx < F4_B) o4[idx] = t4[idx];
        }
    }

    if (t == 0 && bid0 == 0)
        out[(size_t)NB * PER_B] = -1.0f;   // trailing scalar output
}

extern "C" void kernel_launch(void* const* d_in, const int* in_sizes, int n_in,
                              void* d_out, int out_size, void* d_ws, size_t ws_size,
                              hipStream_t stream) {
    const float* x = (const float*)d_in[0];
    float* out = (float*)d_out;
    yolo_kernel<<<dim3(NWG), dim3(THREADS), 0, stream>>>(x, out);
}